// Round 20
// baseline (48.755 us; speedup 1.0000x reference)
//
#include <hip/hip_runtime.h>

typedef float f4 __attribute__((ext_vector_type(4)));
typedef float f32x4 __attribute__((ext_vector_type(4)));
typedef __bf16 bf16x8 __attribute__((ext_vector_type(8)));
typedef __bf16 bf16x4 __attribute__((ext_vector_type(4)));

// out_w fp32 -> bf16 fragment-linear [otile 16][kt 8][m 16][kc 32]
__global__ __launch_bounds__(256) void wcvt(
    const float* __restrict__ wmat, __bf16* __restrict__ wbf)
{
    const int i = (blockIdx.x * 256 + threadIdx.x) * 4;   // o*256+c
    const int o = i >> 8, c = i & 255;
    const f4 v = *(const f4*)&wmat[i];
    bf16x4 ov;
    #pragma unroll
    for (int j = 0; j < 4; ++j) ov[j] = (__bf16)v[j];
    *(bf16x4*)&wbf[((o >> 4) * 8 + (c >> 5)) * 512 + (o & 15) * 32 + (c & 31)] = ov;
}

// Fused attn+proj. Block = (b, patch), 256 thr = 4 waves.
// Wave wv: heads {2wv, 2wv+1} attention (R17 transform-at-read, wave-private
// x slice -> NO barrier) -> midt LDS. One barrier. Then wave wv projects
// otiles 4wv..4wv+3 over the patch's 16 px (kt chunks == heads).
#define XSW(ch_, r_, c_) xsw[wv][(ch_) * 65 + (r_) * 8 + (c_)]

__global__ __launch_bounds__(256) void fused_attn_proj(
    const float* __restrict__ x,
    const float* __restrict__ qkv_w,
    const float* __restrict__ qkv_b,
    const float* __restrict__ pos_table,
    const __bf16* __restrict__ wbf,
    float* __restrict__ y)
{
    __shared__ float  xsw[4][32 * 65];   // 33.3 KB wave-private x slices
    __shared__ __bf16 midt[8][16][40];   // 10.2 KB attn out [head][px][ch]
    __shared__ __bf16 Ps[4][16][72];     // 9.2 KB    total 52.7 KB

    const int t = threadIdx.x;
    const int wv = t >> 6, l = t & 63;
    const int l16 = l & 15, lg = l >> 4;

    const int raw = blockIdx.x;           // 1152 = 8 XCD * 144
    const int sw = (raw & 7) * 144 + (raw >> 3);   // XCD-contiguous patches
    const int b = sw / 576;
    const int patch = sw % 576;
    const int ni = patch / 24, nj = patch % 24;
    const float qscale = 0.17677669529663687f;
    const f32x4 zf = {0.f, 0.f, 0.f, 0.f};

    // stage lane map: ch-group, src row, col-group (2 f4 per row)
    const int ch4 = l >> 4, srow = (l >> 1) & 7, scg = l & 1;
    const int rg = min(4 * ni + srow, 95);

    #pragma unroll
    for (int hp = 0; hp < 2; ++hp) {
        const int h = 2 * wv + hp;
        const int c0 = h * 32;

        // ---- stage wave-private x slice (8x8 px, 32 ch, fp32) ----
        #pragma unroll
        for (int d = 0; d < 8; ++d) {
            const int ch = ch4 * 8 + d;
            const float* xpl = x + (size_t)(b * 256 + c0 + ch) * 9216;
            f4 v;
            if (nj == 23 && scg == 1) {           // cols 96..99 clamp to 95
                const float s = xpl[rg * 96 + 95];
                v = (f4){s, s, s, s};
            } else {
                v = *(const f4*)&xpl[rg * 96 + 4 * nj + 4 * scg];
            }
            float* dst = &XSW(ch, srow, 4 * scg);
            dst[0] = v.x; dst[1] = v.y; dst[2] = v.z; dst[3] = v.w;
        }
        // xsw is wave-private: lgkmcnt ordering suffices, no block barrier.

        // per-lane affine coefficients
        float kw8[8], kb8[8], qw8[8], qb8[8];
        #pragma unroll
        for (int j = 0; j < 8; ++j) {
            const int c = c0 + 8 * lg + j;
            kw8[j] = qkv_w[256 + c];
            kb8[j] = qkv_b[256 + c];
            qw8[j] = qkv_w[c] * qscale;
            qb8[j] = qkv_b[c] * qscale;
        }
        float vw2[2], vb2[2];
        #pragma unroll
        for (int nt = 0; nt < 2; ++nt) {
            const int c = c0 + nt * 16 + l16;
            vw2[nt] = qkv_w[512 + c];
            vb2[nt] = qkv_b[512 + c];
        }

        // ---- Q fragment (own px rows 0..3, cols 0..3) ----
        bf16x8 qf;
        {
            const int qr = l16 >> 2, qc = l16 & 3;
            #pragma unroll
            for (int j = 0; j < 8; ++j)
                qf[j] = (__bf16)(XSW(8 * lg + j, qr, qc) * qw8[j] + qb8[j]);
        }

        // ---- QK^T: 4 x mfma ----
        f32x4 sacc[4];
        #pragma unroll
        for (int t4 = 0; t4 < 4; ++t4) {
            const int px = l16 + 16 * t4;
            const int kr = px >> 3, kc = px & 7;
            bf16x8 kf;
            #pragma unroll
            for (int j = 0; j < 8; ++j)
                kf[j] = (__bf16)(XSW(8 * lg + j, kr, kc) * kw8[j] + kb8[j]);
            sacc[t4] = __builtin_amdgcn_mfma_f32_16x16x32_bf16(qf, kf, zf, 0, 0, 0);
        }

        // ---- bias + row softmax ----
        float sv[4][4], rinv[4];
        #pragma unroll
        for (int rr = 0; rr < 4; ++rr) {
            const int qrow = lg * 4 + rr;
            const int qi = qrow >> 2, qj = qrow & 3;
            float m = -1e30f;
            #pragma unroll
            for (int t4 = 0; t4 < 4; ++t4) {
                const int kcol = l16 + 16 * t4;
                const int ki = kcol >> 3, kj = kcol & 7;
                const float s = sacc[t4][rr]
                    + pos_table[((qi - ki + 7) * 15 + (qj - kj + 7)) * 8 + h];
                sv[t4][rr] = s;
                m = fmaxf(m, s);
            }
            #pragma unroll
            for (int off = 8; off >= 1; off >>= 1)
                m = fmaxf(m, __shfl_xor(m, off, 16));
            float sum = 0.f;
            #pragma unroll
            for (int t4 = 0; t4 < 4; ++t4) {
                const float p = __expf(sv[t4][rr] - m);
                sv[t4][rr] = p;
                sum += p;
            }
            #pragma unroll
            for (int off = 8; off >= 1; off >>= 1)
                sum += __shfl_xor(sum, off, 16);
            rinv[rr] = 1.0f / sum;
            #pragma unroll
            for (int t4 = 0; t4 < 4; ++t4)
                Ps[wv][qrow][l16 + 16 * t4] = (__bf16)sv[t4][rr];
        }
        // Ps wave-private: no barrier.

        // ---- PV ----
        f32x4 oa = zf, ob = zf;
        #pragma unroll
        for (int kt = 0; kt < 2; ++kt) {
            bf16x8 pf = *(const bf16x8*)&Ps[wv][l16][lg * 8 + 32 * kt];
            bf16x8 v0, v1;
            #pragma unroll
            for (int j = 0; j < 8; ++j) {
                const int vr = 4 * kt + lg;
                v0[j] = (__bf16)(XSW(l16,      vr, j) * vw2[0] + vb2[0]);
                v1[j] = (__bf16)(XSW(16 + l16, vr, j) * vw2[1] + vb2[1]);
            }
            oa = __builtin_amdgcn_mfma_f32_16x16x32_bf16(pf, v0, oa, 0, 0, 0);
            ob = __builtin_amdgcn_mfma_f32_16x16x32_bf16(pf, v1, ob, 0, 0, 0);
        }

        // ---- O -> midt (kt chunk == head h) ----
        #pragma unroll
        for (int rr = 0; rr < 4; ++rr) {
            const int qrow = lg * 4 + rr;
            midt[h][qrow][l16]      = (__bf16)(oa[rr] * rinv[rr]);
            midt[h][qrow][16 + l16] = (__bf16)(ob[rr] * rinv[rr]);
        }
    }

    __syncthreads();   // the ONE barrier: midt complete

    // ---- proj phase: wave wv -> otiles 4wv..4wv+3, 16 px ----
    bf16x8 bfr[8];
    #pragma unroll
    for (int kt = 0; kt < 8; ++kt)
        bfr[kt] = *(const bf16x8*)&midt[kt][l16][lg * 8];

    const int fragoff = l16 * 32 + lg * 8;
    const int hh = 4 * ni + (l16 >> 2), ww = 4 * nj + (l16 & 3);
    const size_t ybase = (size_t)b * 256 * 9216 + hh * 96 + ww;

    #pragma unroll
    for (int i = 0; i < 4; ++i) {
        const int ot = 4 * wv + i;
        f32x4 acc = zf;
        #pragma unroll
        for (int kt = 0; kt < 8; ++kt) {
            const bf16x8 af = *(const bf16x8*)&wbf[(ot * 8 + kt) * 512 + fragoff];
            acc = __builtin_amdgcn_mfma_f32_16x16x32_bf16(af, bfr[kt], acc, 0, 0, 0);
        }
        #pragma unroll
        for (int rr = 0; rr < 4; ++rr) {
            const int o = ot * 16 + lg * 4 + rr;
            y[ybase + (size_t)o * 9216] = acc[rr];
        }
    }
}

extern "C" void kernel_launch(void* const* d_in, const int* in_sizes, int n_in,
                              void* d_out, int out_size, void* d_ws, size_t ws_size,
                              hipStream_t stream) {
    const float* x         = (const float*)d_in[0];
    const float* qkv_w     = (const float*)d_in[1];
    const float* qkv_b     = (const float*)d_in[2];
    const float* out_w     = (const float*)d_in[3];
    const float* pos_table = (const float*)d_in[4];
    float* y    = (float*)d_out;
    __bf16* wbf = (__bf16*)d_ws;          // 128 KB; mid eliminated

    wcvt<<<dim3(64), dim3(256), 0, stream>>>(out_w, wbf);
    fused_attn_proj<<<dim3(1152), dim3(256), 0, stream>>>(
        x, qkv_w, qkv_b, pos_table, wbf, y);
}